// Round 1
// baseline (592.654 us; speedup 1.0000x reference)
//
#include <hip/hip_runtime.h>
#include <hip/hip_bf16.h>

// ---------------------------------------------------------------------------
// Feature_Decoder: out = LN(leaky_relu(inp @ Wf^T + bf) * (static @ Wc^T + bc))
// B=32, N=2048, F=512, K_city=256, D=1024.  M = B*N = 65536.
// Plan:
//   k1: convert W_feat fp32 -> bf16 (ws, 1MB)
//   k2: c = static @ Wc^T + bc  (fp32 LDS-tiled, store bf16, ws, 4MB)
//   k3: fused MFMA GEMM (BM=32 x full D=1024) + leaky + gate + LayerNorm
// ---------------------------------------------------------------------------

typedef __attribute__((ext_vector_type(8))) short short8;
typedef __attribute__((ext_vector_type(4))) float f32x4;

__device__ __forceinline__ unsigned short f2bf(float f) {
    unsigned int u = __float_as_uint(f);
    unsigned int r = (u + 0x7FFFu + ((u >> 16) & 1u)) >> 16;   // RNE
    return (unsigned short)r;
}
__device__ __forceinline__ float b2f(unsigned short h) {
    return __uint_as_float(((unsigned int)h) << 16);
}

#define LDS_ASYNC16(g, l) __builtin_amdgcn_global_load_lds(                 \
    (const __attribute__((address_space(1))) void*)(g),                     \
    (__attribute__((address_space(3))) void*)(l), 16, 0, 0)

// ---------------------------------------------------------------------------
// k1: W_feat [1024,512] fp32 -> bf16
// ---------------------------------------------------------------------------
__global__ __launch_bounds__(256) void convw_kernel(
    const float* __restrict__ w, unsigned short* __restrict__ o)
{
    int i = (blockIdx.x * 256 + threadIdx.x) * 4;   // 512 blocks * 256 * 4 = 524288
    float4 v = *(const float4*)(w + i);
    uint2 p;
    p.x = (unsigned)f2bf(v.x) | ((unsigned)f2bf(v.y) << 16);
    p.y = (unsigned)f2bf(v.z) | ((unsigned)f2bf(v.w) << 16);
    *(uint2*)(o + i) = p;
}

// ---------------------------------------------------------------------------
// k2: c[n,d] = dot(static[n,:], Wc[d,:]) + bc[d]   (fp32 compute, bf16 store)
// 32x32 tile per block, K=256 fully staged in LDS.
// ---------------------------------------------------------------------------
__global__ __launch_bounds__(256) void city_kernel(
    const float* __restrict__ st,    // [2048,256]
    const float* __restrict__ Wc,    // [1024,256]
    const float* __restrict__ bc,    // [1024]
    unsigned short* __restrict__ cg) // bf16 [2048,1024]
{
    __shared__ float Ss[32][260];
    __shared__ float Ws[32][260];
    const int tid = threadIdx.x;
    const int n0 = blockIdx.x << 5;
    const int d0 = blockIdx.y << 5;
    #pragma unroll
    for (int i = 0; i < 8; ++i) {
        int idx = (i << 8) + tid;          // 0..2047
        int r   = idx >> 6;
        int c4  = (idx & 63) << 2;
        *(float4*)&Ss[r][c4] = *(const float4*)(st + (size_t)(n0 + r) * 256 + c4);
        *(float4*)&Ws[r][c4] = *(const float4*)(Wc + (size_t)(d0 + r) * 256 + c4);
    }
    __syncthreads();
    const int ti = tid >> 4, tj = tid & 15;
    const int r0 = ti << 1, c0 = tj << 1;
    float a00 = 0.f, a01 = 0.f, a10 = 0.f, a11 = 0.f;
    #pragma unroll 4
    for (int k = 0; k < 256; k += 4) {
        float4 x0 = *(const float4*)&Ss[r0][k];
        float4 x1 = *(const float4*)&Ss[r0 + 1][k];
        float4 y0 = *(const float4*)&Ws[c0][k];
        float4 y1 = *(const float4*)&Ws[c0 + 1][k];
        a00 += x0.x*y0.x + x0.y*y0.y + x0.z*y0.z + x0.w*y0.w;
        a01 += x0.x*y1.x + x0.y*y1.y + x0.z*y1.z + x0.w*y1.w;
        a10 += x1.x*y0.x + x1.y*y0.y + x1.z*y0.z + x1.w*y0.w;
        a11 += x1.x*y1.x + x1.y*y1.y + x1.z*y1.z + x1.w*y1.w;
    }
    const float b0 = bc[d0 + c0], b1 = bc[d0 + c0 + 1];
    cg[(size_t)(n0 + r0    ) * 1024 + d0 + c0    ] = f2bf(a00 + b0);
    cg[(size_t)(n0 + r0    ) * 1024 + d0 + c0 + 1] = f2bf(a01 + b1);
    cg[(size_t)(n0 + r0 + 1) * 1024 + d0 + c0    ] = f2bf(a10 + b0);
    cg[(size_t)(n0 + r0 + 1) * 1024 + d0 + c0 + 1] = f2bf(a11 + b1);
}

// ---------------------------------------------------------------------------
// k3: fused GEMM + leaky_relu + gate + LayerNorm
// Block: 32 rows (one b, 32 consecutive n) x full D=1024. 512 threads = 8 waves.
// Wave w owns cols [w*128, w*128+128): 2 row-tiles x 8 col-tiles of 16x16x32.
// K-loop: BK=32, 16 iters. B staged via global_load_lds (bf16, [d][k] stride 32),
// A staged fp32->bf16 via ds_write (stride 40 = +8 pad, conflict-free frag reads).
// ---------------------------------------------------------------------------
__global__ __launch_bounds__(512, 4) void feat_kernel(
    const float* __restrict__ inp,          // [65536, 512] fp32
    const unsigned short* __restrict__ Wf,  // bf16 [1024, 512]
    const float* __restrict__ b_feat,       // [1024]
    const unsigned short* __restrict__ cg,  // bf16 [2048, 1024]
    const float* __restrict__ gamma,
    const float* __restrict__ beta,
    float* __restrict__ out)                // [65536, 1024] fp32
{
    __shared__ unsigned short Bs[1024 * 32];  // 64 KB: [d][k], stride 32 bf16
    __shared__ unsigned short As[32 * 40];    // 2.5 KB: [m][k], stride 40 (padded)
    __shared__ float red1[8][32];
    __shared__ float red2[8][32];
    __shared__ float smu[32], srs[32];

    const int tid  = threadIdx.x;
    const int lane = tid & 63;
    const int w    = tid >> 6;            // wave 0..7
    const int m0   = blockIdx.x * 32;
    const int n0   = m0 & 2047;           // 2048 % 32 == 0: block never crosses b

    f32x4 acc[2][8];
    #pragma unroll
    for (int i = 0; i < 2; ++i)
        #pragma unroll
        for (int j = 0; j < 8; ++j) acc[i][j] = (f32x4)0.f;

    // A staging: thread -> (row, 2 k-elems)
    const int ar = tid >> 4;              // 0..31
    const int ak = (tid & 15) << 1;       // 0,2,..,30
    const float* aptr = inp + (size_t)(m0 + ar) * 512 + ak;

    // B staging: per wave-issue, 64 lanes x 16B = 16 d-rows of 64B
    const int bd = (w << 4) + (lane >> 2);                    // 0..127
    const unsigned short* bptr = Wf + (size_t)bd * 512 + ((lane & 3) << 3);
    unsigned short* bls = Bs + (w << 9);                      // w*512 elems (wave-uniform)

    const int cl = lane & 15;
    const int q  = lane >> 4;

    for (int kb = 0; kb < 16; ++kb) {
        const int k0 = kb << 5;
        #pragma unroll
        for (int i = 0; i < 8; ++i) {
            // issue i: d rows [i*128, i*128+128), global stride i*128*512 elems
            LDS_ASYNC16(bptr + ((size_t)i << 16) + k0, bls + (i << 12));
        }
        float2 af = *(const float2*)(aptr + k0);
        *(unsigned int*)(As + ar * 40 + ak) =
            (unsigned)f2bf(af.x) | ((unsigned)f2bf(af.y) << 16);
        __syncthreads();

        const unsigned short* arow = As + cl * 40 + (q << 3);
        short8 a0 = *(const short8*)(arow);
        short8 a1 = *(const short8*)(arow + 16 * 40);
        const unsigned short* bbase = Bs + (((w << 7) + cl) << 5) + (q << 3);
        #pragma unroll
        for (int ct = 0; ct < 8; ++ct) {
            short8 b = *(const short8*)(bbase + (ct << 9));   // ct*16 rows * 32
            acc[0][ct] = __builtin_amdgcn_mfma_f32_16x16x32_bf16(a0, b, acc[0][ct], 0, 0, 0);
            acc[1][ct] = __builtin_amdgcn_mfma_f32_16x16x32_bf16(a1, b, acc[1][ct], 0, 0, 0);
        }
        __syncthreads();
    }

    // ---- epilogue: bias + leaky + gate, accumulate per-row sum / sumsq ----
    float s1[2][4], s2[2][4];
    #pragma unroll
    for (int rt = 0; rt < 2; ++rt)
        #pragma unroll
        for (int r = 0; r < 4; ++r) { s1[rt][r] = 0.f; s2[rt][r] = 0.f; }

    #pragma unroll
    for (int ct = 0; ct < 8; ++ct) {
        const int d = (w << 7) + (ct << 4) + cl;
        const float bf = b_feat[d];
        #pragma unroll
        for (int rt = 0; rt < 2; ++rt) {
            #pragma unroll
            for (int r = 0; r < 4; ++r) {
                const int row = (rt << 4) + (q << 2) + r;     // C/D: row=(lane>>4)*4+reg
                float x = acc[rt][ct][r] + bf;
                x = (x >= 0.f) ? x : 0.2f * x;
                x *= b2f(cg[(size_t)(n0 + row) * 1024 + d]);
                acc[rt][ct][r] = x;
                s1[rt][r] += x;
                s2[rt][r] += x * x;
            }
        }
    }
    // reduce across the 16 column-lanes (bits 0..3 of lane)
    #pragma unroll
    for (int off = 1; off < 16; off <<= 1) {
        #pragma unroll
        for (int rt = 0; rt < 2; ++rt)
            #pragma unroll
            for (int r = 0; r < 4; ++r) {
                s1[rt][r] += __shfl_xor(s1[rt][r], off, 64);
                s2[rt][r] += __shfl_xor(s2[rt][r], off, 64);
            }
    }
    if (cl == 0) {
        #pragma unroll
        for (int rt = 0; rt < 2; ++rt)
            #pragma unroll
            for (int r = 0; r < 4; ++r) {
                const int row = (rt << 4) + (q << 2) + r;
                red1[w][row] = s1[rt][r];
                red2[w][row] = s2[rt][r];
            }
    }
    __syncthreads();
    if (tid < 32) {
        float a = 0.f, b = 0.f;
        #pragma unroll
        for (int j = 0; j < 8; ++j) { a += red1[j][tid]; b += red2[j][tid]; }
        const float mu  = a * (1.0f / 1024.0f);
        const float var = b * (1.0f / 1024.0f) - mu * mu;
        smu[tid] = mu;
        srs[tid] = rsqrtf(var + 1e-5f);
    }
    __syncthreads();

    #pragma unroll
    for (int ct = 0; ct < 8; ++ct) {
        const int d = (w << 7) + (ct << 4) + cl;
        const float g = gamma[d], be = beta[d];
        #pragma unroll
        for (int rt = 0; rt < 2; ++rt) {
            #pragma unroll
            for (int r = 0; r < 4; ++r) {
                const int row = (rt << 4) + (q << 2) + r;
                out[(size_t)(m0 + row) * 1024 + d] =
                    (acc[rt][ct][r] - smu[row]) * srs[row] * g + be;
            }
        }
    }
}

// ---------------------------------------------------------------------------
extern "C" void kernel_launch(void* const* d_in, const int* in_sizes, int n_in,
                              void* d_out, int out_size, void* d_ws, size_t ws_size,
                              hipStream_t stream) {
    const float* inp   = (const float*)d_in[0];   // [32,2048,512]
    const float* st    = (const float*)d_in[1];   // [2048,256]
    const float* Wf    = (const float*)d_in[2];   // [1024,512]
    const float* bfeat = (const float*)d_in[3];   // [1024]
    const float* Wc    = (const float*)d_in[4];   // [1024,256]
    const float* bc    = (const float*)d_in[5];   // [1024]
    const float* gamma = (const float*)d_in[6];   // [1024]
    const float* beta  = (const float*)d_in[7];   // [1024]
    float* out = (float*)d_out;

    unsigned short* wsWf = (unsigned short*)d_ws;                     // 1 MB bf16 W_feat
    unsigned short* wsC  = (unsigned short*)((char*)d_ws + (1 << 20)); // 4 MB bf16 c

    convw_kernel<<<512, 256, 0, stream>>>(Wf, wsWf);
    city_kernel<<<dim3(64, 32), 256, 0, stream>>>(st, Wc, bc, wsC);
    feat_kernel<<<2048, 512, 0, stream>>>(inp, wsWf, bfeat, wsC, gamma, beta, out);
}

// Round 2
// 580.239 us; speedup vs baseline: 1.0214x; 1.0214x over previous
//
#include <hip/hip_runtime.h>
#include <hip/hip_bf16.h>

// ---------------------------------------------------------------------------
// Feature_Decoder: out = LN(leaky_relu(inp @ Wf^T + bf) * (static @ Wc^T + bc))
// B=32, N=2048, F=512, K_city=256, D=1024.  M = B*N = 65536.
//   k1 convw: W_feat fp32 -> bf16 (ws, 1 MB)
//   k2 city : c = static @ Wc^T + bc, MFMA bf16, store bf16 (ws, 4 MB)
//   k3 feat : BM=64 x full-D MFMA GEMM, LDS double-buffered, fused
//             bias+leaky+gate+LayerNorm epilogue
// ---------------------------------------------------------------------------

typedef __attribute__((ext_vector_type(8))) short short8;
typedef __attribute__((ext_vector_type(4))) float f32x4;

__device__ __forceinline__ unsigned short f2bf(float f) {
    unsigned int u = __float_as_uint(f);
    return (unsigned short)((u + 0x7FFFu + ((u >> 16) & 1u)) >> 16);   // RNE
}
__device__ __forceinline__ float b2f(unsigned short h) {
    return __uint_as_float(((unsigned int)h) << 16);
}

#define LDS_ASYNC16(g, l) __builtin_amdgcn_global_load_lds(                 \
    (const __attribute__((address_space(1))) void*)(g),                     \
    (__attribute__((address_space(3))) void*)(l), 16, 0, 0)

// ---------------------------------------------------------------------------
// k1: W_feat [1024,512] fp32 -> bf16
// ---------------------------------------------------------------------------
__global__ __launch_bounds__(256) void convw_kernel(
    const float* __restrict__ w, unsigned short* __restrict__ o)
{
    int i = (blockIdx.x * 256 + threadIdx.x) * 4;
    float4 v = *(const float4*)(w + i);
    uint2 p;
    p.x = (unsigned)f2bf(v.x) | ((unsigned)f2bf(v.y) << 16);
    p.y = (unsigned)f2bf(v.z) | ((unsigned)f2bf(v.w) << 16);
    *(uint2*)(o + i) = p;
}

// ---------------------------------------------------------------------------
// k2: c[n,d] = dot(static[n,:], Wc[d,:]) + bc[d]  via MFMA bf16.
// Tile 64(n) x 128(d) per block, whole K=256 staged in LDS (fp32->bf16 inline).
// Grid 32 x 8 = 256 blocks = exactly 1 per CU. 256 threads = 4 waves.
// ---------------------------------------------------------------------------
__global__ __launch_bounds__(256) void city_kernel(
    const float* __restrict__ st,    // [2048,256]
    const float* __restrict__ Wc,    // [1024,256]
    const float* __restrict__ bc,    // [1024]
    unsigned short* __restrict__ cg) // bf16 [2048,1024]
{
    __shared__ __align__(16) unsigned short Sa[64 * 264];
    __shared__ __align__(16) unsigned short Sb[128 * 264];
    const int t  = threadIdx.x;
    const int n0 = blockIdx.x << 6;
    const int d0 = blockIdx.y << 7;

    #pragma unroll
    for (int i = 0; i < 16; ++i) {
        int idx = (i << 8) + t;
        int row = idx >> 6, kq = (idx & 63) << 2;
        float4 v = *(const float4*)(st + (size_t)(n0 + row) * 256 + kq);
        uint2 p;
        p.x = (unsigned)f2bf(v.x) | ((unsigned)f2bf(v.y) << 16);
        p.y = (unsigned)f2bf(v.z) | ((unsigned)f2bf(v.w) << 16);
        *(uint2*)(Sa + row * 264 + kq) = p;
    }
    #pragma unroll
    for (int i = 0; i < 32; ++i) {
        int idx = (i << 8) + t;
        int row = idx >> 6, kq = (idx & 63) << 2;
        float4 v = *(const float4*)(Wc + (size_t)(d0 + row) * 256 + kq);
        uint2 p;
        p.x = (unsigned)f2bf(v.x) | ((unsigned)f2bf(v.y) << 16);
        p.y = (unsigned)f2bf(v.z) | ((unsigned)f2bf(v.w) << 16);
        *(uint2*)(Sb + row * 264 + kq) = p;
    }
    __syncthreads();

    const int wv = t >> 6;            // wave 0..3 -> d strip wv*32
    const int cl = t & 15, q = (t >> 4) & 3;
    f32x4 acc[4][2];
    #pragma unroll
    for (int rt = 0; rt < 4; ++rt)
        #pragma unroll
        for (int ct = 0; ct < 2; ++ct) acc[rt][ct] = (f32x4)0.f;

    #pragma unroll
    for (int ks = 0; ks < 8; ++ks) {
        short8 a[4];
        #pragma unroll
        for (int rt = 0; rt < 4; ++rt)
            a[rt] = *(const short8*)(Sa + ((rt << 4) + cl) * 264 + (ks << 5) + (q << 3));
        #pragma unroll
        for (int ct = 0; ct < 2; ++ct) {
            short8 bf8 = *(const short8*)(Sb + ((wv << 5) + (ct << 4) + cl) * 264 + (ks << 5) + (q << 3));
            #pragma unroll
            for (int rt = 0; rt < 4; ++rt)
                acc[rt][ct] = __builtin_amdgcn_mfma_f32_16x16x32_bf16(a[rt], bf8, acc[rt][ct], 0, 0, 0);
        }
    }
    #pragma unroll
    for (int ct = 0; ct < 2; ++ct) {
        const int d = d0 + (wv << 5) + (ct << 4) + cl;
        const float bcv = bc[d];
        #pragma unroll
        for (int rt = 0; rt < 4; ++rt)
            #pragma unroll
            for (int rr = 0; rr < 4; ++rr) {
                const int row = (rt << 4) + (q << 2) + rr;   // C/D: row=(lane>>4)*4+reg
                cg[(size_t)(n0 + row) * 1024 + d] = f2bf(acc[rt][ct][rr] + bcv);
            }
    }
}

// ---------------------------------------------------------------------------
// k3: fused GEMM + leaky + gate + LayerNorm.
// Block = 64 rows x full D=1024. 512 threads = 8 waves; wave w: cols [w*128,+128).
// K-loop BK=32, 16 iters, LDS double-buffered; B staged via global_load_lds
// width=16 into swizzled [kchunk][d16] regions (all 32 banks on frag reads);
// A staged fp32->bf16 via ds_write (stride 40 shorts, 16B-aligned frags).
// ---------------------------------------------------------------------------
__global__ __launch_bounds__(512, 2) void feat_kernel(
    const float* __restrict__ inp,          // [65536, 512] fp32
    const unsigned short* __restrict__ Wf,  // bf16 [1024, 512]
    const float* __restrict__ b_feat,       // [1024]
    const unsigned short* __restrict__ cg,  // bf16 [2048, 1024]
    const float* __restrict__ gamma,
    const float* __restrict__ beta,
    float* __restrict__ out)                // [65536, 1024] fp32
{
    __shared__ __align__(16) unsigned short Bs[2][32768];  // 2 x 64 KB
    __shared__ __align__(16) unsigned short As[2][2560];   // 2 x 5 KB (64 x 40)

    const int t    = threadIdx.x;
    const int lane = t & 63;
    const int w    = t >> 6;            // wave 0..7
    const int cl   = lane & 15;
    const int q    = lane >> 4;
    const int m0   = blockIdx.x << 6;
    const int n0   = m0 & 2047;         // 2048 % 64 == 0: block never crosses b

    f32x4 acc[4][8];
    #pragma unroll
    for (int rt = 0; rt < 4; ++rt)
        #pragma unroll
        for (int ct = 0; ct < 8; ++ct) acc[rt][ct] = (f32x4)0.f;

    // A staging: thread -> (row = t>>3, 4 consecutive k at (t&7)*4)
    const int arow = t >> 3, akq = (t & 7) << 2;
    const float* ap = inp + (size_t)(m0 + arow) * 512 + akq;

    // B staging: lane l of wave w loads Wf[w*16 + (l&15)][k0 + (l>>4)*8 .. +7]
    // -> slot-identity image: region (d>>4), slot = kchunk*16 + (d&15)
    const unsigned short* bgp = Wf + (size_t)((w << 4) + cl) * 512 + (q << 3);

    // ---- prologue: stage kb=0 into buffer 0 ----
    #pragma unroll
    for (int i = 0; i < 8; ++i)
        LDS_ASYNC16(bgp + ((size_t)i << 16), &Bs[0][(w << 9) + (i << 12)]);
    {
        float4 av = *(const float4*)ap;
        uint2 p;
        p.x = (unsigned)f2bf(av.x) | ((unsigned)f2bf(av.y) << 16);
        p.y = (unsigned)f2bf(av.z) | ((unsigned)f2bf(av.w) << 16);
        *(uint2*)(&As[0][arow * 40 + akq]) = p;
    }
    __syncthreads();

    for (int kb = 0; kb < 16; ++kb) {
        const int b = kb & 1;
        float4 av;
        if (kb < 15) {
            const int k0n = (kb + 1) << 5;
            #pragma unroll
            for (int i = 0; i < 8; ++i)
                LDS_ASYNC16(bgp + k0n + ((size_t)i << 16), &Bs[b ^ 1][(w << 9) + (i << 12)]);
            av = *(const float4*)(ap + k0n);
        }
        // compute on buffer b
        short8 a[4];
        #pragma unroll
        for (int rt = 0; rt < 4; ++rt)
            a[rt] = *(const short8*)(&As[b][((rt << 4) + cl) * 40 + (q << 3)]);
        #pragma unroll
        for (int ct = 0; ct < 8; ++ct) {
            short8 bf8 = *(const short8*)(&Bs[b][(((w << 3) + ct) << 9) + (q << 7) + (cl << 3)]);
            #pragma unroll
            for (int rt = 0; rt < 4; ++rt)
                acc[rt][ct] = __builtin_amdgcn_mfma_f32_16x16x32_bf16(a[rt], bf8, acc[rt][ct], 0, 0, 0);
        }
        if (kb < 15) {
            uint2 p;
            p.x = (unsigned)f2bf(av.x) | ((unsigned)f2bf(av.y) << 16);
            p.y = (unsigned)f2bf(av.z) | ((unsigned)f2bf(av.w) << 16);
            *(uint2*)(&As[b ^ 1][arow * 40 + akq]) = p;
        }
        __syncthreads();
    }

    // ---- epilogue: bias + leaky + gate, LN stats, normalize, store ----
    // reduction scratch overlaid on As (compute done; last barrier protects)
    float* red1 = (float*)&As[0][0];     // [8][64]
    float* red2 = red1 + 512;            // [8][64]
    float* smu  = red1 + 1024;           // [64]
    float* srs  = red1 + 1088;           // [64]

    float bfv[8];
    #pragma unroll
    for (int ct = 0; ct < 8; ++ct) bfv[ct] = b_feat[(w << 7) + (ct << 4) + cl];

    #pragma unroll
    for (int rt = 0; rt < 4; ++rt) {
        #pragma unroll
        for (int rr = 0; rr < 4; ++rr) {
            const int row = (rt << 4) + (q << 2) + rr;
            float s1 = 0.f, s2 = 0.f;
            #pragma unroll
            for (int ct = 0; ct < 8; ++ct) {
                const int d = (w << 7) + (ct << 4) + cl;
                float x = acc[rt][ct][rr] + bfv[ct];
                x = (x >= 0.f) ? x : 0.2f * x;
                x *= b2f(cg[(size_t)(n0 + row) * 1024 + d]);
                acc[rt][ct][rr] = x;
                s1 += x;
                s2 += x * x;
            }
            #pragma unroll
            for (int off = 1; off < 16; off <<= 1) {
                s1 += __shfl_xor(s1, off, 64);
                s2 += __shfl_xor(s2, off, 64);
            }
            if (cl == 0) {
                red1[(w << 6) + row] = s1;
                red2[(w << 6) + row] = s2;
            }
        }
    }
    __syncthreads();
    if (t < 64) {
        float a = 0.f, bb = 0.f;
        #pragma unroll
        for (int j = 0; j < 8; ++j) { a += red1[(j << 6) + t]; bb += red2[(j << 6) + t]; }
        const float mu  = a * (1.0f / 1024.0f);
        const float var = bb * (1.0f / 1024.0f) - mu * mu;
        smu[t] = mu;
        srs[t] = rsqrtf(var + 1e-5f);
    }
    __syncthreads();

    #pragma unroll
    for (int ct = 0; ct < 8; ++ct) {
        const int d = (w << 7) + (ct << 4) + cl;
        const float g = gamma[d], be = beta[d];
        #pragma unroll
        for (int rt = 0; rt < 4; ++rt) {
            #pragma unroll
            for (int rr = 0; rr < 4; ++rr) {
                const int row = (rt << 4) + (q << 2) + rr;
                out[(size_t)(m0 + row) * 1024 + d] =
                    (acc[rt][ct][rr] - smu[row]) * srs[row] * g + be;
            }
        }
    }
}

// ---------------------------------------------------------------------------
extern "C" void kernel_launch(void* const* d_in, const int* in_sizes, int n_in,
                              void* d_out, int out_size, void* d_ws, size_t ws_size,
                              hipStream_t stream) {
    const float* inp   = (const float*)d_in[0];   // [32,2048,512]
    const float* st    = (const float*)d_in[1];   // [2048,256]
    const float* Wf    = (const float*)d_in[2];   // [1024,512]
    const float* bfeat = (const float*)d_in[3];   // [1024]
    const float* Wc    = (const float*)d_in[4];   // [1024,256]
    const float* bc    = (const float*)d_in[5];   // [1024]
    const float* gamma = (const float*)d_in[6];   // [1024]
    const float* beta  = (const float*)d_in[7];   // [1024]
    float* out = (float*)d_out;

    unsigned short* wsWf = (unsigned short*)d_ws;                      // 1 MB bf16 W_feat
    unsigned short* wsC  = (unsigned short*)((char*)d_ws + (1 << 20)); // 4 MB bf16 c

    convw_kernel<<<512, 256, 0, stream>>>(Wf, wsWf);
    city_kernel<<<dim3(32, 8), 256, 0, stream>>>(st, Wc, bc, wsC);
    feat_kernel<<<1024, 512, 0, stream>>>(inp, wsWf, bfeat, wsC, gamma, beta, out);
}